// Round 7
// baseline (135.716 us; speedup 1.0000x reference)
//
#include <hip/hip_runtime.h>
#include <hip/hip_fp16.h>

#define NT 256

constexpr int TABLE_SZ = 721 * 1441;

// superquad: per level-0 cell, one 64 B cache line:
//   4 levels x {e0,e1,e2,e3} as __half2 (feat pairs) = 4 x uint4
constexpr int QLAT = 181, QLON = 361;      // level-0 cell index ranges
constexpr int NCELLS = QLAT * QLON;        // 65341 cells -> 4.18 MB

// per-(level,row) LUT: rows 181 + 91 + 46 + 23 = 341 entries of {ca, inv_n2}
constexpr int LUT_OFF0 = 0, LUT_OFF1 = 181, LUT_OFF2 = 272, LUT_OFF3 = 318;
constexpr int LUT_N = 341;

typedef float v4f __attribute__((ext_vector_type(4)));
typedef float v2f __attribute__((ext_vector_type(2)));

__device__ __constant__ float c_s2_tab[4] = {0.008726535498f, 0.017452406437f,
                                             0.034899496703f, 0.069756473744f};

// one thread per (cell, level): 261k threads, coalesced uint4 stores
__global__ __launch_bounds__(256)
void build_superquad(const float* __restrict__ emb, uint4* __restrict__ sq)
{
    int t = blockIdx.x * 256 + threadIdx.x;
    if (t >= NCELLS * 4) return;
    const int c = t >> 2;
    const int i = t & 3;
    const int la = c / QLON, lo = c - la * QLON;
    const int width = 1440 >> i;
    const int ra = la >> i, co = lo >> i;           // level-i cell (floor identity)
    const float2* tb = (const float2*)emb + (size_t)i * TABLE_SZ;
    float2 e0 = tb[ra * width + co];
    float2 e1 = tb[ra * width + co + 1];
    float2 e2 = tb[(ra + 1) * width + co];
    float2 e3 = tb[(ra + 1) * width + co + 1];
    union { uint4 u; __half2 h[4]; } pk;
    pk.h[0] = __floats2half2_rn(e0.x, e0.y);
    pk.h[1] = __floats2half2_rn(e1.x, e1.y);
    pk.h[2] = __floats2half2_rn(e2.x, e2.y);
    pk.h[3] = __floats2half2_rn(e3.x, e3.y);
    sq[t] = pk.u;
}

__global__ __launch_bounds__(NT)
void ngp_interp_kernel(const float* __restrict__ x,
                       const uint4* __restrict__ sq,
                       float* __restrict__ out,
                       int B)
{
    const float r = 0.017453292519943295f;   // pi/180 in fp32
    const float bmin_lat = -90.25f;
    const float bmin_lon = -0.25f;

    // ---- tiny LUT: {ca, inv_n2} per (level, lat-row); bit-identical math ----
    __shared__ float2 lut[LUT_N];
    for (int t = threadIdx.x; t < LUT_N; t += NT) {
        int lvl, row;
        if (t < LUT_OFF1)      { lvl = 0; row = t; }
        else if (t < LUT_OFF2) { lvl = 1; row = t - LUT_OFF1; }
        else if (t < LUT_OFF3) { lvl = 2; row = t - LUT_OFF2; }
        else                   { lvl = 3; row = t - LUT_OFF3; }
        const float gs = (float)(1 << lvl);
        const float gmin_lat = (float)row * gs + bmin_lat;
        const float ca = fabsf(__cosf(gmin_lat * r));
        const float z2 = ca * c_s2_tab[lvl];
        const float n2 = z2 + z2 * z2 * z2 * (1.0f / 6.0f);
        lut[t] = make_float2(ca, __builtin_amdgcn_rcpf(n2));
    }
    __syncthreads();

    // ---- 2 points per thread ----
    const int p0 = (blockIdx.x * NT + threadIdx.x) * 2;
    if (p0 >= B) return;     // B even => p0+1 < B whenever p0 < B

    const v4f xp = __builtin_nontemporal_load(
        reinterpret_cast<const v4f*>(x) + (p0 >> 1));   // {lat0,lon0,lat1,lon1}
    const float xla[2] = {xp.x, xp.z};
    const float xlo[2] = {xp.y, xp.w};

    const float bmax_lat = 90.25f, bmax_lon = 360.25f;

    float vla[2], vlo[2];
    uint4 q[2][4];
    #pragma unroll
    for (int k = 0; k < 2; ++k) {
        const float xc_lat = fminf(fmaxf(xla[k], bmin_lat), bmax_lat);
        const float xc_lon = fminf(fmaxf(xlo[k], bmin_lon), bmax_lon);
        vla[k] = xc_lat - bmin_lat;   // [0, 180.5]
        vlo[k] = xc_lon - bmin_lon;   // [0, 360.5]
        const int cell0 = (int)floorf(vla[k]) * QLON + (int)floorf(vlo[k]);
        const uint4* cellp = sq + (size_t)cell0 * 4;
        #pragma unroll
        for (int i = 0; i < 4; ++i) q[k][i] = cellp[i];   // both 64B lines in flight
    }

    float o[16];

    #pragma unroll
    for (int k = 0; k < 2; ++k) {
        #pragma unroll
        for (int i = 0; i < 4; ++i) {
            const float gs     = (float)(1 << i);
            const float inv_gs = 1.0f / gs;     // gs pow2: mul == div exactly
            const int   loff   = (i == 0) ? LUT_OFF0 : (i == 1) ? LUT_OFF1
                                 : (i == 2) ? LUT_OFF2 : LUT_OFF3;

            // bl bit-identical to np: fp32 sub, exact pow2 div, floor
            const float blat_f = floorf(vla[k] * inv_gs);
            const float blon_f = floorf(vlo[k] * inv_gs);
            const float gmin_lat = blat_f * gs + bmin_lat;
            const float gmin_lon = blon_f * gs + bmin_lon;
            const float gmax_lon = gmin_lon + gs;
            const int bl_lat = (int)blat_f;

            union { uint4 u; __half2 h[4]; } pk;
            pk.u = q[k][i];
            const float2 f0 = __half22float2(pk.h[0]);
            const float2 f1 = __half22float2(pk.h[1]);
            const float2 f2 = __half22float2(pk.h[2]);
            const float2 f3 = __half22float2(pk.h[3]);

            // wlat: meridian geodesic ratio == (x_lat - gmin_lat) / gs
            const float wlat = (xla[k] - gmin_lat) * inv_gs;

            // wlon via LUT (bit-identical to inline version)
            const float2 cl = lut[loff + bl_lat];
            const float h1 = (gmax_lon - xlo[k]) * r * 0.5f;        // <= 0.0699 rad
            const float s1 = h1 - h1 * h1 * h1 * (1.0f / 6.0f);     // sin(h1)
            const float z1 = cl.x * s1;
            const float n1 = z1 + z1 * z1 * z1 * (1.0f / 6.0f);     // asin(z1)
            const float wlon = n1 * cl.y;

            const float c0x = f0.x + (f2.x - f0.x) * wlat;
            const float c0y = f0.y + (f2.y - f0.y) * wlat;
            const float c1x = f1.x + (f3.x - f1.x) * wlat;
            const float c1y = f1.y + (f3.y - f1.y) * wlat;
            o[k * 8 + 2 * i]     = c0x + (c1x - c0x) * wlon;
            o[k * 8 + 2 * i + 1] = c0y + (c1y - c0y) * wlon;
        }
    }

    // 64 B contiguous per thread — streaming, nontemporal
    v4f* op = reinterpret_cast<v4f*>(out + (size_t)p0 * 8);
    #pragma unroll
    for (int j = 0; j < 4; ++j) {
        v4f v = {o[4 * j], o[4 * j + 1], o[4 * j + 2], o[4 * j + 3]};
        __builtin_nontemporal_store(v, op + j);
    }
}

// fallback (no workspace): original per-point gather from raw table
__global__ __launch_bounds__(NT)
void ngp_interp_fallback(const float* __restrict__ x,
                         const float* __restrict__ emb,
                         float* __restrict__ out,
                         int B)
{
    const int p = blockIdx.x * NT + threadIdx.x;
    if (p >= B) return;
    const float xlat = x[(size_t)p * 2], xlon = x[(size_t)p * 2 + 1];
    const float bmin_lat = -90.25f, bmax_lat = 90.25f;
    const float bmin_lon = -0.25f,  bmax_lon = 360.25f;
    const float xc_lat = fminf(fmaxf(xlat, bmin_lat), bmax_lat);
    const float xc_lon = fminf(fmaxf(xlon, bmin_lon), bmax_lon);
    const float r = 0.017453292519943295f;
    float o[8];
    #pragma unroll
    for (int i = 0; i < 4; ++i) {
        const float gs = (float)(1 << i), inv_gs = 1.0f / gs;
        const int width = 1440 >> i;
        const float blat_f = floorf((xc_lat - bmin_lat) * inv_gs);
        const float blon_f = floorf((xc_lon - bmin_lon) * inv_gs);
        const float gmin_lat = blat_f * gs + bmin_lat;
        const float gmin_lon = blon_f * gs + bmin_lon;
        const float gmax_lon = gmin_lon + gs;
        const int idx00 = (int)blat_f * width + (int)blon_f;
        const float* base0 = emb + ((size_t)i * TABLE_SZ + (size_t)idx00) * 2;
        const float* base1 = base0 + (size_t)width * 2;
        v4f eA, eB;
        __builtin_memcpy(&eA, base0, 16);
        __builtin_memcpy(&eB, base1, 16);
        const float wlat = (xlat - gmin_lat) * inv_gs;
        const float ca = fabsf(__cosf(gmin_lat * r));
        const float h1 = (gmax_lon - xlon) * r * 0.5f;
        const float s1 = h1 - h1 * h1 * h1 * (1.0f / 6.0f);
        const float z1 = ca * s1;
        const float z2 = ca * c_s2_tab[i];
        const float n1 = z1 + z1 * z1 * z1 * (1.0f / 6.0f);
        const float n2 = z2 + z2 * z2 * z2 * (1.0f / 6.0f);
        const float wlon = n1 * __builtin_amdgcn_rcpf(n2);
        const float c0x = eA.x + (eB.x - eA.x) * wlat;
        const float c0y = eA.y + (eB.y - eA.y) * wlat;
        const float c1x = eA.z + (eB.z - eA.z) * wlat;
        const float c1y = eA.w + (eB.w - eA.w) * wlat;
        o[2*i]   = c0x + (c1x - c0x) * wlon;
        o[2*i+1] = c0y + (c1y - c0y) * wlon;
    }
    v4f* op = reinterpret_cast<v4f*>(out + (size_t)p * 8);
    v4f lo = {o[0], o[1], o[2], o[3]};
    v4f hi = {o[4], o[5], o[6], o[7]};
    __builtin_nontemporal_store(lo, op);
    __builtin_nontemporal_store(hi, op + 1);
}

extern "C" void kernel_launch(void* const* d_in, const int* in_sizes, int n_in,
                              void* d_out, int out_size, void* d_ws, size_t ws_size,
                              hipStream_t stream)
{
    const float* x   = (const float*)d_in[0];   // (B, 2) fp32
    const float* emb = (const float*)d_in[1];   // (4, TABLE, 2) fp32
    float* out = (float*)d_out;                 // (B, 8) fp32
    const int B = in_sizes[0] / 2;

    const size_t sq_bytes = (size_t)NCELLS * 64;
    if (ws_size >= sq_bytes && (B % 2) == 0) {
        uint4* sq = (uint4*)d_ws;
        build_superquad<<<(NCELLS * 4 + 255) / 256, 256, 0, stream>>>(emb, sq);
        const int npair = B / 2;
        ngp_interp_kernel<<<(npair + NT - 1) / NT, NT, 0, stream>>>(x, sq, out, B);
    } else {
        ngp_interp_fallback<<<(B + NT - 1) / NT, NT, 0, stream>>>(x, emb, out, B);
    }
}